// Round 4
// baseline (92.589 us; speedup 1.0000x reference)
//
#include <hip/hip_runtime.h>
#include <math.h>

// Loss: per row i of output/target (B x 3 f32):
//   ang = 2*pi*(x-0.5); v = euler_to_vec(ang); per = 1 - |cross(vo,vt)| + dot(vo,vt)
//   result = sum over B.
//
// R3 design notes:
// - v_sin/v_cos take REVOLUTIONS: sin(2*pi*(x-0.5)) == __builtin_amdgcn_sinf(x-0.5f).
// - R1 vs R2 showed the wall is the L2-miss/fabric path to Infinity Cache
//   (~5.3 TB/s effective; inputs are fully L3-resident in steady state).
//   Staging layout changes don't move it. Remaining waste was the second
//   kernel launch + 1-block final reduce (~4-5us of 38us) -> fuse the final
//   reduction into the main kernel with a last-block ticket (agent-scope
//   atomics; 4-byte memsetAsync resets the ticket each call, so every
//   launch does identical work — graph-replay safe).

#define NBLOCKS 1024
#define NTHREADS 512
#define TILE_ROWS 1024                 // rows per block-iteration
#define TILE_F2 (TILE_ROWS * 3 / 2)    // 1536 float2 per input = 12 KB

__device__ __forceinline__ float sample_loss(float a, float b, float c,
                                             float d, float e, float f) {
  float oy = a - 0.5f, op = b - 0.5f, orr = c - 0.5f;
  float ty = d - 0.5f, tp = e - 0.5f, trr = f - 0.5f;

  float cy = __builtin_amdgcn_cosf(oy), sy = __builtin_amdgcn_sinf(oy);
  float cp = __builtin_amdgcn_cosf(op), sp = __builtin_amdgcn_sinf(op);
  float cr = __builtin_amdgcn_cosf(orr), sr = __builtin_amdgcn_sinf(orr);

  float vox = cy * sp * cr + sy * sr;
  float voy = sy * sp * cr - cy * sr;
  float voz = cp * cr;

  float cy2 = __builtin_amdgcn_cosf(ty), sy2 = __builtin_amdgcn_sinf(ty);
  float cp2 = __builtin_amdgcn_cosf(tp), sp2 = __builtin_amdgcn_sinf(tp);
  float cr2 = __builtin_amdgcn_cosf(trr), sr2 = __builtin_amdgcn_sinf(trr);

  float vtx = cy2 * sp2 * cr2 + sy2 * sr2;
  float vty = sy2 * sp2 * cr2 - cy2 * sr2;
  float vtz = cp2 * cr2;

  float crx = voy * vtz - voz * vty;
  float cry = voz * vtx - vox * vtz;
  float crz = vox * vty - voy * vtx;

  float cn = sqrtf(crx * crx + cry * cry + crz * crz);
  float dot = vox * vtx + voy * vty + voz * vtz;
  return 1.0f - cn + dot;
}

template <int NT>
__device__ __forceinline__ float block_reduce(float acc) {
  #pragma unroll
  for (int off = 32; off > 0; off >>= 1) acc += __shfl_down(acc, off, 64);
  __shared__ float ws[NT / 64];
  int lane = threadIdx.x & 63;
  int wave = threadIdx.x >> 6;
  if (lane == 0) ws[wave] = acc;
  __syncthreads();
  float tot = 0.0f;
  if (threadIdx.x == 0) {
    #pragma unroll
    for (int w = 0; w < NT / 64; ++w) tot += ws[w];
  }
  __syncthreads();  // allow re-entry (second call reuses ws)
  return tot;       // valid in thread 0 only
}

__global__ __launch_bounds__(NTHREADS) void loss_kernel(
    const float* __restrict__ out, const float* __restrict__ tgt,
    float* __restrict__ partial, unsigned int* __restrict__ counter,
    float* __restrict__ result, int B) {
  __shared__ float2 ldsO2[TILE_F2];
  __shared__ float2 ldsT2[TILE_F2];
  const float* ldsO = (const float*)ldsO2;
  const float* ldsT = (const float*)ldsT2;

  const float2* __restrict__ o2 = (const float2*)out;
  const float2* __restrict__ t2 = (const float2*)tgt;

  const int t = threadIdx.x;
  const int ntiles = B / TILE_ROWS;

  float acc = 0.0f;

  int tile = blockIdx.x;
  float2 a0, a1, a2, b0, b1, b2;
  if (tile < ntiles) {
    const int g = tile * TILE_F2 + t;
    a0 = o2[g]; a1 = o2[g + NTHREADS]; a2 = o2[g + 2 * NTHREADS];
    b0 = t2[g]; b1 = t2[g + NTHREADS]; b2 = t2[g + 2 * NTHREADS];
  }

  while (tile < ntiles) {
    ldsO2[t] = a0; ldsO2[t + NTHREADS] = a1; ldsO2[t + 2 * NTHREADS] = a2;
    ldsT2[t] = b0; ldsT2[t + NTHREADS] = b1; ldsT2[t + 2 * NTHREADS] = b2;
    __syncthreads();

    // issue NEXT tile's global loads now; latency hides under compute.
    const int next = tile + gridDim.x;
    if (next < ntiles) {
      const int g = next * TILE_F2 + t;
      a0 = o2[g]; a1 = o2[g + NTHREADS]; a2 = o2[g + 2 * NTHREADS];
      b0 = t2[g]; b1 = t2[g + NTHREADS]; b2 = t2[g + 2 * NTHREADS];
    }

    #pragma unroll
    for (int k = 0; k < TILE_ROWS / NTHREADS; ++k) {
      const int r = t + k * NTHREADS;
      acc += sample_loss(ldsO[3 * r], ldsO[3 * r + 1], ldsO[3 * r + 2],
                         ldsT[3 * r], ldsT[3 * r + 1], ldsT[3 * r + 2]);
    }
    __syncthreads();
    tile = next;
  }

  // tail rows (B not divisible by TILE_ROWS) — scalar, distributed
  const int done = ntiles * TILE_ROWS;
  for (int r = done + blockIdx.x * NTHREADS + t; r < B;
       r += gridDim.x * NTHREADS) {
    acc += sample_loss(out[3 * r], out[3 * r + 1], out[3 * r + 2],
                       tgt[3 * r], tgt[3 * r + 1], tgt[3 * r + 2]);
  }

  float tot = block_reduce<NTHREADS>(acc);

  // last-block final reduction (ticket pattern, agent scope for cross-XCD)
  __shared__ int lastFlag;
  if (t == 0) {
    __hip_atomic_store(&partial[blockIdx.x], tot, __ATOMIC_RELEASE,
                       __HIP_MEMORY_SCOPE_AGENT);
    unsigned int ticket = __hip_atomic_fetch_add(
        counter, 1u, __ATOMIC_ACQ_REL, __HIP_MEMORY_SCOPE_AGENT);
    lastFlag = (ticket == gridDim.x - 1);
  }
  __syncthreads();
  if (lastFlag) {
    float a = 0.0f;
    for (int i = t; i < (int)gridDim.x; i += NTHREADS)
      a += __hip_atomic_load(&partial[i], __ATOMIC_RELAXED,
                             __HIP_MEMORY_SCOPE_AGENT);
    float tot2 = block_reduce<NTHREADS>(a);
    if (t == 0) result[0] = tot2;
  }
}

extern "C" void kernel_launch(void* const* d_in, const int* in_sizes, int n_in,
                              void* d_out, int out_size, void* d_ws, size_t ws_size,
                              hipStream_t stream) {
  const float* d_output = (const float*)d_in[0];
  const float* d_target = (const float*)d_in[1];
  float* partial = (float*)d_ws;                      // NBLOCKS floats
  unsigned int* counter = (unsigned int*)((char*)d_ws + NBLOCKS * sizeof(float));
  float* out = (float*)d_out;                         // 1 float
  const int B = in_sizes[0] / 3;

  hipMemsetAsync(counter, 0, sizeof(unsigned int), stream);
  loss_kernel<<<NBLOCKS, NTHREADS, 0, stream>>>(d_output, d_target, partial,
                                                counter, out, B);
}

// Round 5
// 42.092 us; speedup vs baseline: 2.1997x; 2.1997x over previous
//
#include <hip/hip_runtime.h>
#include <math.h>

// Loss: per row i of output/target (B x 3 f32):
//   ang = 2*pi*(x-0.5); v = euler_to_vec(ang); per = 1 - |cross(vo,vt)| + dot(vo,vt)
//   result = sum over B.
//
// R4 design notes:
// - v_sin/v_cos take REVOLUTIONS: sin(2*pi*(x-0.5)) == __builtin_amdgcn_sinf(x-0.5f).
// - R1 vs R2: access pattern doesn't move the ~6 TB/s read wall (L3-resident,
//   fabric-path ceiling). Main kernel is at the wall.
// - R3 lesson: ordered AGENT-scope atomics (release wbl2 / acquire inv) at
//   block-retire poisoned the streaming caches for co-resident blocks -> 2x
//   regression. R4 uses ONE plain relaxed atomicAdd per block into d_out[0]
//   (no cache maintenance), with a 4-byte memsetAsync zeroing d_out in the
//   same capture (harness does not re-poison between replays).

#define NBLOCKS 1024
#define NTHREADS 512
#define TILE_ROWS 1024                 // rows per block-iteration
#define TILE_F2 (TILE_ROWS * 3 / 2)    // 1536 float2 per input = 12 KB

__device__ __forceinline__ float sample_loss(float a, float b, float c,
                                             float d, float e, float f) {
  float oy = a - 0.5f, op = b - 0.5f, orr = c - 0.5f;
  float ty = d - 0.5f, tp = e - 0.5f, trr = f - 0.5f;

  float cy = __builtin_amdgcn_cosf(oy), sy = __builtin_amdgcn_sinf(oy);
  float cp = __builtin_amdgcn_cosf(op), sp = __builtin_amdgcn_sinf(op);
  float cr = __builtin_amdgcn_cosf(orr), sr = __builtin_amdgcn_sinf(orr);

  float vox = cy * sp * cr + sy * sr;
  float voy = sy * sp * cr - cy * sr;
  float voz = cp * cr;

  float cy2 = __builtin_amdgcn_cosf(ty), sy2 = __builtin_amdgcn_sinf(ty);
  float cp2 = __builtin_amdgcn_cosf(tp), sp2 = __builtin_amdgcn_sinf(tp);
  float cr2 = __builtin_amdgcn_cosf(trr), sr2 = __builtin_amdgcn_sinf(trr);

  float vtx = cy2 * sp2 * cr2 + sy2 * sr2;
  float vty = sy2 * sp2 * cr2 - cy2 * sr2;
  float vtz = cp2 * cr2;

  float crx = voy * vtz - voz * vty;
  float cry = voz * vtx - vox * vtz;
  float crz = vox * vty - voy * vtx;

  float cn = sqrtf(crx * crx + cry * cry + crz * crz);
  float dot = vox * vtx + voy * vty + voz * vtz;
  return 1.0f - cn + dot;
}

template <int NT>
__device__ __forceinline__ float block_reduce(float acc) {
  #pragma unroll
  for (int off = 32; off > 0; off >>= 1) acc += __shfl_down(acc, off, 64);
  __shared__ float ws[NT / 64];
  int lane = threadIdx.x & 63;
  int wave = threadIdx.x >> 6;
  if (lane == 0) ws[wave] = acc;
  __syncthreads();
  float tot = 0.0f;
  if (threadIdx.x == 0) {
    #pragma unroll
    for (int w = 0; w < NT / 64; ++w) tot += ws[w];
  }
  return tot;  // valid in thread 0 only
}

__global__ __launch_bounds__(NTHREADS) void loss_kernel(
    const float* __restrict__ out, const float* __restrict__ tgt,
    float* __restrict__ result, int B) {
  __shared__ float2 ldsO2[TILE_F2];
  __shared__ float2 ldsT2[TILE_F2];
  const float* ldsO = (const float*)ldsO2;
  const float* ldsT = (const float*)ldsT2;

  const float2* __restrict__ o2 = (const float2*)out;
  const float2* __restrict__ t2 = (const float2*)tgt;

  const int t = threadIdx.x;
  const int ntiles = B / TILE_ROWS;

  float acc = 0.0f;

  int tile = blockIdx.x;
  float2 a0, a1, a2, b0, b1, b2;
  if (tile < ntiles) {
    const int g = tile * TILE_F2 + t;
    a0 = o2[g]; a1 = o2[g + NTHREADS]; a2 = o2[g + 2 * NTHREADS];
    b0 = t2[g]; b1 = t2[g + NTHREADS]; b2 = t2[g + 2 * NTHREADS];
  }

  while (tile < ntiles) {
    ldsO2[t] = a0; ldsO2[t + NTHREADS] = a1; ldsO2[t + 2 * NTHREADS] = a2;
    ldsT2[t] = b0; ldsT2[t + NTHREADS] = b1; ldsT2[t + 2 * NTHREADS] = b2;
    __syncthreads();

    // issue NEXT tile's global loads now; latency hides under compute.
    const int next = tile + gridDim.x;
    if (next < ntiles) {
      const int g = next * TILE_F2 + t;
      a0 = o2[g]; a1 = o2[g + NTHREADS]; a2 = o2[g + 2 * NTHREADS];
      b0 = t2[g]; b1 = t2[g + NTHREADS]; b2 = t2[g + 2 * NTHREADS];
    }

    #pragma unroll
    for (int k = 0; k < TILE_ROWS / NTHREADS; ++k) {
      const int r = t + k * NTHREADS;
      acc += sample_loss(ldsO[3 * r], ldsO[3 * r + 1], ldsO[3 * r + 2],
                         ldsT[3 * r], ldsT[3 * r + 1], ldsT[3 * r + 2]);
    }
    __syncthreads();
    tile = next;
  }

  // tail rows (B not divisible by TILE_ROWS) — scalar, distributed
  const int done = ntiles * TILE_ROWS;
  for (int r = done + blockIdx.x * NTHREADS + t; r < B;
       r += gridDim.x * NTHREADS) {
    acc += sample_loss(out[3 * r], out[3 * r + 1], out[3 * r + 2],
                       tgt[3 * r], tgt[3 * r + 1], tgt[3 * r + 2]);
  }

  float tot = block_reduce<NTHREADS>(acc);

  // One relaxed device-scope float atomicAdd per block. No ordering ops ->
  // no cache-maintenance (the R3 failure mode). d_out is zeroed by the
  // memsetAsync captured in the same graph, so replays accumulate from 0.
  if (t == 0) atomicAdd(result, tot);
}

extern "C" void kernel_launch(void* const* d_in, const int* in_sizes, int n_in,
                              void* d_out, int out_size, void* d_ws, size_t ws_size,
                              hipStream_t stream) {
  const float* d_output = (const float*)d_in[0];
  const float* d_target = (const float*)d_in[1];
  float* out = (float*)d_out;  // 1 float
  const int B = in_sizes[0] / 3;

  hipMemsetAsync(out, 0, sizeof(float), stream);
  loss_kernel<<<NBLOCKS, NTHREADS, 0, stream>>>(d_output, d_target, out, B);
}

// Round 6
// 38.593 us; speedup vs baseline: 2.3991x; 1.0906x over previous
//
#include <hip/hip_runtime.h>
#include <math.h>

// Loss: per row i of output/target (B x 3 f32):
//   ang = 2*pi*(x-0.5); v = euler_to_vec(ang); per = 1 - |cross(vo,vt)| + dot(vo,vt)
//   result = sum over B.
//
// R5 design notes:
// - v_sin/v_cos take REVOLUTIONS: sin(2*pi*(x-0.5)) == __builtin_amdgcn_sinf(x-0.5f).
// - Main loop is at ~5.7 TB/s effective (L3-resident read-once; three different
//   structures all plateau here). R5 probes the last lever: non-temporal (nt)
//   loads so read-once data doesn't thrash L2 retention.
// - R3 lesson: ordered agent-scope atomics flush caches -> 2x regression.
// - R4 lesson: hipMemsetAsync in the captured graph = SDMA node; the
//   SDMA<->compute semaphore round-trip (~4us) costs more than a tiny second
//   kernel. Keep the deterministic two-kernel shape, slim the final kernel
//   to one wave (no LDS, no barriers).

#define NBLOCKS 1024
#define NTHREADS 512
#define TILE_ROWS 1024                 // rows per block-iteration
#define TILE_F2 (TILE_ROWS * 3 / 2)    // 1536 float2 per input = 12 KB

__device__ __forceinline__ float2 ntload2(const double* p) {
  // nt-bit 8B load; bitcast to float2 (HIP float2 is a class, so load as double)
  double d = __builtin_nontemporal_load(p);
  return __builtin_bit_cast(float2, d);
}

__device__ __forceinline__ float sample_loss(float a, float b, float c,
                                             float d, float e, float f) {
  float oy = a - 0.5f, op = b - 0.5f, orr = c - 0.5f;
  float ty = d - 0.5f, tp = e - 0.5f, trr = f - 0.5f;

  float cy = __builtin_amdgcn_cosf(oy), sy = __builtin_amdgcn_sinf(oy);
  float cp = __builtin_amdgcn_cosf(op), sp = __builtin_amdgcn_sinf(op);
  float cr = __builtin_amdgcn_cosf(orr), sr = __builtin_amdgcn_sinf(orr);

  float vox = cy * sp * cr + sy * sr;
  float voy = sy * sp * cr - cy * sr;
  float voz = cp * cr;

  float cy2 = __builtin_amdgcn_cosf(ty), sy2 = __builtin_amdgcn_sinf(ty);
  float cp2 = __builtin_amdgcn_cosf(tp), sp2 = __builtin_amdgcn_sinf(tp);
  float cr2 = __builtin_amdgcn_cosf(trr), sr2 = __builtin_amdgcn_sinf(trr);

  float vtx = cy2 * sp2 * cr2 + sy2 * sr2;
  float vty = sy2 * sp2 * cr2 - cy2 * sr2;
  float vtz = cp2 * cr2;

  float crx = voy * vtz - voz * vty;
  float cry = voz * vtx - vox * vtz;
  float crz = vox * vty - voy * vtx;

  float cn = sqrtf(crx * crx + cry * cry + crz * crz);
  float dot = vox * vtx + voy * vty + voz * vtz;
  return 1.0f - cn + dot;
}

template <int NT>
__device__ __forceinline__ float block_reduce(float acc) {
  #pragma unroll
  for (int off = 32; off > 0; off >>= 1) acc += __shfl_down(acc, off, 64);
  __shared__ float ws[NT / 64];
  int lane = threadIdx.x & 63;
  int wave = threadIdx.x >> 6;
  if (lane == 0) ws[wave] = acc;
  __syncthreads();
  float tot = 0.0f;
  if (threadIdx.x == 0) {
    #pragma unroll
    for (int w = 0; w < NT / 64; ++w) tot += ws[w];
  }
  return tot;  // valid in thread 0 only
}

__global__ __launch_bounds__(NTHREADS) void loss_partial_kernel(
    const float* __restrict__ out, const float* __restrict__ tgt,
    float* __restrict__ partial, int B) {
  __shared__ float2 ldsO2[TILE_F2];
  __shared__ float2 ldsT2[TILE_F2];
  const float* ldsO = (const float*)ldsO2;
  const float* ldsT = (const float*)ldsT2;

  const double* __restrict__ o2 = (const double*)out;  // 8B elements
  const double* __restrict__ t2 = (const double*)tgt;

  const int t = threadIdx.x;
  const int ntiles = B / TILE_ROWS;

  float acc = 0.0f;

  int tile = blockIdx.x;
  float2 a0, a1, a2, b0, b1, b2;
  if (tile < ntiles) {
    const int g = tile * TILE_F2 + t;
    a0 = ntload2(o2 + g); a1 = ntload2(o2 + g + NTHREADS); a2 = ntload2(o2 + g + 2 * NTHREADS);
    b0 = ntload2(t2 + g); b1 = ntload2(t2 + g + NTHREADS); b2 = ntload2(t2 + g + 2 * NTHREADS);
  }

  while (tile < ntiles) {
    ldsO2[t] = a0; ldsO2[t + NTHREADS] = a1; ldsO2[t + 2 * NTHREADS] = a2;
    ldsT2[t] = b0; ldsT2[t + NTHREADS] = b1; ldsT2[t + 2 * NTHREADS] = b2;
    __syncthreads();

    // issue NEXT tile's global loads now; latency hides under compute.
    const int next = tile + gridDim.x;
    if (next < ntiles) {
      const int g = next * TILE_F2 + t;
      a0 = ntload2(o2 + g); a1 = ntload2(o2 + g + NTHREADS); a2 = ntload2(o2 + g + 2 * NTHREADS);
      b0 = ntload2(t2 + g); b1 = ntload2(t2 + g + NTHREADS); b2 = ntload2(t2 + g + 2 * NTHREADS);
    }

    #pragma unroll
    for (int k = 0; k < TILE_ROWS / NTHREADS; ++k) {
      const int r = t + k * NTHREADS;
      acc += sample_loss(ldsO[3 * r], ldsO[3 * r + 1], ldsO[3 * r + 2],
                         ldsT[3 * r], ldsT[3 * r + 1], ldsT[3 * r + 2]);
    }
    __syncthreads();
    tile = next;
  }

  // tail rows (B not divisible by TILE_ROWS) — scalar, distributed
  const int done = ntiles * TILE_ROWS;
  for (int r = done + blockIdx.x * NTHREADS + t; r < B;
       r += gridDim.x * NTHREADS) {
    acc += sample_loss(out[3 * r], out[3 * r + 1], out[3 * r + 2],
                       tgt[3 * r], tgt[3 * r + 1], tgt[3 * r + 2]);
  }

  float tot = block_reduce<NTHREADS>(acc);
  if (t == 0) partial[blockIdx.x] = tot;
}

// One wave, pure shuffle reduce — no LDS, no __syncthreads. All 1024 loads
// issue up front (16/thread in flight), ~1us latency-bound.
__global__ __launch_bounds__(64) void final_reduce_kernel(
    const float* __restrict__ partial, int n, float* __restrict__ out) {
  float acc = 0.0f;
  for (int i = threadIdx.x; i < n; i += 64) acc += partial[i];
  #pragma unroll
  for (int off = 32; off > 0; off >>= 1) acc += __shfl_down(acc, off, 64);
  if (threadIdx.x == 0) out[0] = acc;
}

extern "C" void kernel_launch(void* const* d_in, const int* in_sizes, int n_in,
                              void* d_out, int out_size, void* d_ws, size_t ws_size,
                              hipStream_t stream) {
  const float* d_output = (const float*)d_in[0];
  const float* d_target = (const float*)d_in[1];
  float* partial = (float*)d_ws;  // NBLOCKS floats of scratch
  float* out = (float*)d_out;     // 1 float
  const int B = in_sizes[0] / 3;

  loss_partial_kernel<<<NBLOCKS, NTHREADS, 0, stream>>>(d_output, d_target,
                                                        partial, B);
  final_reduce_kernel<<<1, 64, 0, stream>>>(partial, NBLOCKS, out);
}